// Round 7
// baseline (1235.840 us; speedup 1.0000x reference)
//
#include <hip/hip_runtime.h>
#include <hip/hip_bf16.h>
#include <stdint.h>

// out[8192,4096] = x[8192,2048] @ WeffT^T ; WeffT built from W (4096,2048).
#define M_DIM 8192
#define K_DIM 2048
#define N_DIM 4096
#define BM 256
#define BN 256
#define BK 32
#define NT (K_DIM / BK)    // 64 K-tiles
#define NITER (NT / 2)     // 32 iterations, 2 K-tiles each

typedef __attribute__((ext_vector_type(8))) short bf16x8;
typedef __attribute__((ext_vector_type(4))) float f32x4;

__device__ __forceinline__ unsigned short f2bfu(float f) {
    __hip_bfloat16 h = __float2bfloat16(f);
    return __builtin_bit_cast(unsigned short, h);
}

// ---------------------------------------------------------------------------
// Fused prep (one dispatch), unchanged from R6 (proven, ~35 us ~ HBM floor):
//   blocks [0, 2048):  WeffT rows {2b, 2b+1} (paired streams)
//   blocks [2048, 2048+16384): x fp32 -> bf16
// ---------------------------------------------------------------------------
__global__ __launch_bounds__(256) void prep_fused(const float* __restrict__ x,
                                                  const float* __restrict__ W,
                                                  unsigned short* __restrict__ xb,
                                                  unsigned short* __restrict__ wt) {
    const int bid = blockIdx.x;
    if (bid < N_DIM / 2) {
        __shared__ float row0[K_DIM];
        __shared__ float row1[K_DIM];
        const int o0 = bid * 2;
        const float* w0 = W + (size_t)o0 * K_DIM;
        const float* w1 = W + (size_t)(o0 + 1) * K_DIM;
#pragma unroll
        for (int t = 0; t < 2; ++t) {
            ((float4*)row0)[threadIdx.x + 256 * t] = ((const float4*)w0)[threadIdx.x + 256 * t];
            ((float4*)row1)[threadIdx.x + 256 * t] = ((const float4*)w1)[threadIdx.x + 256 * t];
        }
        __syncthreads();

        const float* rF0 = W + (size_t)(N_DIM - 1 - o0) * K_DIM;
        const float* rF1 = W + (size_t)(N_DIM - 2 - o0) * K_DIM;
        const float* rm1 = W + (size_t)((o0 - 1) & (N_DIM - 1)) * K_DIM;
        const float* rm2 = W + (size_t)((o0 - 2) & (N_DIM - 1)) * K_DIM;
        const float* rm3 = W + (size_t)((o0 - 3) & (N_DIM - 1)) * K_DIM;
        const float* rm4 = W + (size_t)((o0 - 4) & (N_DIM - 1)) * K_DIM;
        const float* rm5 = W + (size_t)((o0 - 5) & (N_DIM - 1)) * K_DIM;
        unsigned short* wo0 = wt + (size_t)o0 * K_DIM;
        unsigned short* wo1 = wo0 + K_DIM;

#pragma unroll
        for (int t = 0; t < 2; ++t) {
            const int i0 = (threadIdx.x + 256 * t) * 4;
            const float4 vF0 = *(const float4*)(rF0 + i0);
            const float4 vF1 = *(const float4*)(rF1 + i0);
            const float4 v1  = *(const float4*)(rm1 + i0);
            const float4 v2  = *(const float4*)(rm2 + i0);
            const float4 v3  = *(const float4*)(rm3 + i0);
            const float4 v4  = *(const float4*)(rm4 + i0);
            const float4 v5  = *(const float4*)(rm5 + i0);
            ushort4 ov0, ov1;
#pragma unroll
            for (int j = 0; j < 4; ++j) {
                const int i = i0 + j;
                float s0 = row0[i] + row0[K_DIM - 1 - i]
                         + row0[(i - 1) & (K_DIM - 1)] + row0[(i - 2) & (K_DIM - 1)]
                         + row0[(i - 3) & (K_DIM - 1)] + row0[(i - 4) & (K_DIM - 1)]
                         + row0[(i - 5) & (K_DIM - 1)];
                s0 += (&vF0.x)[j] + (&v1.x)[j] + (&v2.x)[j]
                    + (&v3.x)[j] + (&v4.x)[j] + (&v5.x)[j];
                (&ov0.x)[j] = f2bfu(s0);

                float s1 = row1[i] + row1[K_DIM - 1 - i]
                         + row1[(i - 1) & (K_DIM - 1)] + row1[(i - 2) & (K_DIM - 1)]
                         + row1[(i - 3) & (K_DIM - 1)] + row1[(i - 4) & (K_DIM - 1)]
                         + row1[(i - 5) & (K_DIM - 1)];
                s1 += (&vF1.x)[j] + row0[i] + (&v1.x)[j] + (&v2.x)[j]
                    + (&v3.x)[j] + (&v4.x)[j];
                (&ov1.x)[j] = f2bfu(s1);
            }
            *(ushort4*)(wo0 + i0) = ov0;
            *(ushort4*)(wo1 + i0) = ov1;
        }
    } else {
        const int idx = (bid - N_DIM / 2) * 256 + threadIdx.x;
        float4 v = ((const float4*)x)[idx];
        ushort4 o;
        o.x = f2bfu(v.x); o.y = f2bfu(v.y); o.z = f2bfu(v.z); o.w = f2bfu(v.w);
        ((ushort4*)xb)[idx] = o;
    }
}

// ---------------------------------------------------------------------------
// GEMM R7: 256x256 / BK=32 / 8 waves (2Mx4N) / 64 KiB LDS -> 2 blocks/CU.
// Per-phase shape IDENTICAL to R6 (16 MFMA + ds_reads + 2 gload_lds + 2
// barriers), 128 phases total; only buffer geometry + ledger changed.
//
// LDS per buffer p (32 KiB @ p*32768): A[256][32]bf16 @0 (h0 rows 0-127,
// h1 @8192), B @16384 (same halves). Row = 64 B = 4 x 16B slots; physical
// slot = logical ^ (row&3), applied on BOTH pre-swizzled global source and
// ds_read addr (rule #21). Bank-balance verified (all 8 bank-quads x 8 lanes).
//
// Iteration u: tile 2u in buf0 (ph1: B+A[fmh0], ph2: A[fmh1]);
//              tile 2u+1 in buf1 (ph3, ph4 same).
// Stage ledger (2 units/phase; unit = 128 rows x 32 = 8 KB = 1 inst/thread):
//   ph1: (2u+1).A -> buf1.A  (freed by prev ph4)
//   ph2: (2u+2).B -> buf0.B  (freed by ph1)   + vmcnt(2)  [forces (2u+1).A]
//   ph3: (2u+2).A -> buf0.A  (freed by ph2)
//   ph4: (2u+3).B -> buf1.B  (freed by ph3)   + vmcnt(2)  [forces (2u+2).B,A]
// Every unit forced exactly 2 phases after issue; newest 2 loads stay in
// flight. Prologue: t0.B,t0.A,t1.B + vmcnt(2). Last iter: ph2 vmcnt(0),
// stages of t>=NT guarded out.
// ---------------------------------------------------------------------------
__global__ __launch_bounds__(512, 4) void gemm8p(const unsigned short* __restrict__ Ab,
                                                 const unsigned short* __restrict__ Bt,
                                                 float* __restrict__ C) {
    __shared__ __align__(16) char smem[2 * 32768];

    const int tid  = threadIdx.x;
    const int wave = tid >> 6;
    const int lane = tid & 63;

    // XCD-bijective swizzle (nwg = 512, % 8 == 0)
    const int nwg = gridDim.x;
    const int cpx = nwg >> 3;
    const int wg  = (blockIdx.x & 7) * cpx + (blockIdx.x >> 3);
    const int nbn = N_DIM / BN;                 // 16
    const int bm0 = (wg / nbn) * BM;
    const int bn0 = (wg % nbn) * BN;

    const int wr = wave >> 2;                   // 0..1 (M)
    const int wc = wave & 3;                    // 0..3 (N)

    // ---- staging (pre-swizzled global source); unit = 128 rows x 32 cols ----
    const int srow = tid >> 2;                          // 0..127
    const int lsw  = (lane & 3) ^ ((lane >> 2) & 3);    // logical slot fetched
    const unsigned short* gA0 = Ab + (size_t)(bm0 + srow) * K_DIM + lsw * 8;
    const unsigned short* gB0 = Bt + (size_t)(bn0 + srow) * K_DIM + lsw * 8;

    // ---- ds_read addressing (4 slots, XOR row&3; conflict-balanced) ----
    const int r16  = lane & 15;
    const int sl   = (((lane >> 4)) ^ (r16 & 3)) * 16;  // phys slot byte
    const int aBase = (wr * 128 + r16) * 64 + sl;       // + fmh*4096 + fm*1024
    const int bBase = 16384 + (wc * 64 + r16) * 64 + sl; // + fn*1024

    f32x4  acc[8][4] = {};
    bf16x8 b[4];

#define STAGE_UNIT(gbase, opoff, h, t, p) do {                                              \
    char* lds_ = smem + (p) * 32768 + (opoff) + (h) * 8192 + wave * 1024;                   \
    const unsigned short* g_ = (gbase) + (size_t)((h) * 128) * K_DIM + (t) * BK;            \
    __builtin_amdgcn_global_load_lds(                                                        \
        (const __attribute__((address_space(1))) unsigned int*)g_,                           \
        (__attribute__((address_space(3))) unsigned int*)lds_, 16, 0, 0);                    \
} while (0)

#define STAGE_AB(gbase, opoff, t, p) do {                                                   \
    STAGE_UNIT(gbase, opoff, 0, t, p);                                                      \
    STAGE_UNIT(gbase, opoff, 1, t, p);                                                      \
} while (0)

#define PHASE(P, FMH, LOADB, STAGE_STMT, VM_STMT) do {                                      \
    const char* base_ = smem + (P) * 32768;                                                 \
    bf16x8 a_[4];                                                                           \
    if (LOADB) {                                                                            \
        _Pragma("unroll")                                                                   \
        for (int fn = 0; fn < 4; ++fn)                                                      \
            b[fn] = *(const bf16x8*)(base_ + bBase + fn * 1024);                            \
    }                                                                                       \
    _Pragma("unroll")                                                                       \
    for (int fm = 0; fm < 4; ++fm)                                                          \
        a_[fm] = *(const bf16x8*)(base_ + aBase + (FMH) * 4096 + fm * 1024);                \
    STAGE_STMT;                                                                             \
    __builtin_amdgcn_s_barrier();                                                           \
    asm volatile("s_waitcnt lgkmcnt(0)" ::: "memory");                                      \
    __builtin_amdgcn_sched_barrier(0);                                                      \
    __builtin_amdgcn_s_setprio(1);                                                          \
    _Pragma("unroll")                                                                       \
    for (int fm = 0; fm < 4; ++fm)                                                          \
        _Pragma("unroll")                                                                   \
        for (int fn = 0; fn < 4; ++fn)                                                      \
            acc[(FMH) * 4 + fm][fn] = __builtin_amdgcn_mfma_f32_16x16x32_bf16(              \
                a_[fm], b[fn], acc[(FMH) * 4 + fm][fn], 0, 0, 0);                           \
    __builtin_amdgcn_s_setprio(0);                                                          \
    VM_STMT;                                                                                \
    __builtin_amdgcn_s_barrier();                                                           \
} while (0)

    // ---- prologue: t0.B, t0.A, t1.B; t1.B may stay in flight ----
    STAGE_AB(gB0, 16384, 0, 0);
    STAGE_AB(gA0, 0,     0, 0);
    STAGE_AB(gB0, 16384, 1, 1);
    asm volatile("s_waitcnt vmcnt(2)" ::: "memory");
    __builtin_amdgcn_s_barrier();

    for (int u = 0; u < NITER; ++u) {
        const bool last = (u == NITER - 1);
        const int  t1 = 2 * u + 1, t2 = 2 * u + 2, t3 = 2 * u + 3;

        PHASE(0, 0, 1, { STAGE_AB(gA0, 0, t1, 1); }, {});                       // t1.A
        PHASE(0, 1, 0, { if (!last) STAGE_AB(gB0, 16384, t2, 0); },             // t2.B
              { if (last) asm volatile("s_waitcnt vmcnt(0)" ::: "memory");
                else      asm volatile("s_waitcnt vmcnt(2)" ::: "memory"); });
        PHASE(1, 0, 1, { if (!last) STAGE_AB(gA0, 0, t2, 0); }, {});            // t2.A
        PHASE(1, 1, 0, { if (!last) STAGE_AB(gB0, 16384, t3, 1); },             // t3.B
              { if (!last) asm volatile("s_waitcnt vmcnt(2)" ::: "memory"); });
    }
#undef PHASE
#undef STAGE_AB
#undef STAGE_UNIT

    // ---- epilogue: D col = lane&15, row = (lane>>4)*4 + r ----
    const int crow = (lane >> 4) * 4;
    const int ccol = lane & 15;
    float* Cb = C + (size_t)(bm0 + wr * 128 + crow) * N_DIM + (bn0 + wc * 64 + ccol);
#pragma unroll
    for (int fm = 0; fm < 8; ++fm)
#pragma unroll
        for (int fn = 0; fn < 4; ++fn)
#pragma unroll
            for (int r = 0; r < 4; ++r)
                Cb[(size_t)(fm * 16 + r) * N_DIM + fn * 16] = acc[fm][fn][r];
}

// ---------------------------------------------------------------------------
extern "C" void kernel_launch(void* const* d_in, const int* in_sizes, int n_in,
                              void* d_out, int out_size, void* d_ws, size_t ws_size,
                              hipStream_t stream) {
    const float* x = (const float*)d_in[0];   // (4,2048,2048) fp32
    const float* W = (const float*)d_in[1];   // (4096,2048) fp32
    float* out = (float*)d_out;               // (4,2048,4096) fp32

    unsigned short* xb = (unsigned short*)d_ws;                                      // 32 MB bf16 x
    unsigned short* wt = (unsigned short*)((char*)d_ws + (size_t)M_DIM * K_DIM * 2); // 16 MB WeffT

    const int cvt_blocks = (M_DIM * K_DIM) / 4 / 256;   // 16384
    prep_fused<<<N_DIM / 2 + cvt_blocks, 256, 0, stream>>>(x, W, xb, wt);

    dim3 grid((M_DIM / BM) * (N_DIM / BN));   // 512 blocks, 2 per CU
    gemm8p<<<grid, 512, 0, stream>>>(xb, wt, out);
}

// Round 8
// 163.976 us; speedup vs baseline: 7.5367x; 7.5367x over previous
//
#include <hip/hip_runtime.h>
#include <hip/hip_bf16.h>
#include <stdint.h>

// out[8192,4096] = x[8192,2048] @ WeffT^T ; WeffT built from W (4096,2048).
#define M_DIM 8192
#define K_DIM 2048
#define N_DIM 4096
#define BM 256
#define BN 256
#define BK 64
#define NT (K_DIM / BK)    // 32 K-tiles
#define NITER (NT / 2)     // 16 iterations, 2 K-tiles each

typedef __attribute__((ext_vector_type(8))) short bf16x8;
typedef __attribute__((ext_vector_type(4))) float f32x4;

__device__ __forceinline__ unsigned short f2bfu(float f) {
    __hip_bfloat16 h = __float2bfloat16(f);
    return __builtin_bit_cast(unsigned short, h);
}

// ---------------------------------------------------------------------------
// Fused prep (one dispatch), unchanged from R6 (proven, ~35 us):
//   blocks [0, 2048):  WeffT rows {2b, 2b+1} (paired streams)
//   blocks [2048, 2048+16384): x fp32 -> bf16
// ---------------------------------------------------------------------------
__global__ __launch_bounds__(256) void prep_fused(const float* __restrict__ x,
                                                  const float* __restrict__ W,
                                                  unsigned short* __restrict__ xb,
                                                  unsigned short* __restrict__ wt) {
    const int bid = blockIdx.x;
    if (bid < N_DIM / 2) {
        __shared__ float row0[K_DIM];
        __shared__ float row1[K_DIM];
        const int o0 = bid * 2;
        const float* w0 = W + (size_t)o0 * K_DIM;
        const float* w1 = W + (size_t)(o0 + 1) * K_DIM;
#pragma unroll
        for (int t = 0; t < 2; ++t) {
            ((float4*)row0)[threadIdx.x + 256 * t] = ((const float4*)w0)[threadIdx.x + 256 * t];
            ((float4*)row1)[threadIdx.x + 256 * t] = ((const float4*)w1)[threadIdx.x + 256 * t];
        }
        __syncthreads();

        const float* rF0 = W + (size_t)(N_DIM - 1 - o0) * K_DIM;
        const float* rF1 = W + (size_t)(N_DIM - 2 - o0) * K_DIM;
        const float* rm1 = W + (size_t)((o0 - 1) & (N_DIM - 1)) * K_DIM;
        const float* rm2 = W + (size_t)((o0 - 2) & (N_DIM - 1)) * K_DIM;
        const float* rm3 = W + (size_t)((o0 - 3) & (N_DIM - 1)) * K_DIM;
        const float* rm4 = W + (size_t)((o0 - 4) & (N_DIM - 1)) * K_DIM;
        const float* rm5 = W + (size_t)((o0 - 5) & (N_DIM - 1)) * K_DIM;
        unsigned short* wo0 = wt + (size_t)o0 * K_DIM;
        unsigned short* wo1 = wo0 + K_DIM;

#pragma unroll
        for (int t = 0; t < 2; ++t) {
            const int i0 = (threadIdx.x + 256 * t) * 4;
            const float4 vF0 = *(const float4*)(rF0 + i0);
            const float4 vF1 = *(const float4*)(rF1 + i0);
            const float4 v1  = *(const float4*)(rm1 + i0);
            const float4 v2  = *(const float4*)(rm2 + i0);
            const float4 v3  = *(const float4*)(rm3 + i0);
            const float4 v4  = *(const float4*)(rm4 + i0);
            const float4 v5  = *(const float4*)(rm5 + i0);
            ushort4 ov0, ov1;
#pragma unroll
            for (int j = 0; j < 4; ++j) {
                const int i = i0 + j;
                float s0 = row0[i] + row0[K_DIM - 1 - i]
                         + row0[(i - 1) & (K_DIM - 1)] + row0[(i - 2) & (K_DIM - 1)]
                         + row0[(i - 3) & (K_DIM - 1)] + row0[(i - 4) & (K_DIM - 1)]
                         + row0[(i - 5) & (K_DIM - 1)];
                s0 += (&vF0.x)[j] + (&v1.x)[j] + (&v2.x)[j]
                    + (&v3.x)[j] + (&v4.x)[j] + (&v5.x)[j];
                (&ov0.x)[j] = f2bfu(s0);

                float s1 = row1[i] + row1[K_DIM - 1 - i]
                         + row1[(i - 1) & (K_DIM - 1)] + row1[(i - 2) & (K_DIM - 1)]
                         + row1[(i - 3) & (K_DIM - 1)] + row1[(i - 4) & (K_DIM - 1)]
                         + row1[(i - 5) & (K_DIM - 1)];
                s1 += (&vF1.x)[j] + row0[i] + (&v1.x)[j] + (&v2.x)[j]
                    + (&v3.x)[j] + (&v4.x)[j];
                (&ov1.x)[j] = f2bfu(s1);
            }
            *(ushort4*)(wo0 + i0) = ov0;
            *(ushort4*)(wo1 + i0) = ov1;
        }
    } else {
        const int idx = (bid - N_DIM / 2) * 256 + threadIdx.x;
        float4 v = ((const float4*)x)[idx];
        ushort4 o;
        o.x = f2bfu(v.x); o.y = f2bfu(v.y); o.z = f2bfu(v.z); o.w = f2bfu(v.w);
        ((ushort4*)xb)[idx] = o;
    }
}

// ---------------------------------------------------------------------------
// GEMM: R6 K-loop verbatim (256x256 / BK=64 / 8 waves / 8-phase / 3-half-deep
// vmcnt(6)) + R8 epilogue: per-wave LDS-transpose -> dwordx4 C stores.
//
// LDS per buffer p (64 KiB @ p*65536): A @0 (A0 rows0-127, A1 @16384),
// B @32768 (B0, B1 @49152). Row=128B=8x16B slots, physical slot =
// logical ^ (row&7), both-sides swizzle (rule #21). Proven 0 conflicts.
//
// Stage ledger (steady state):
//   ph1: t1.A1->buf1   ph2: t2.B0->buf0   ph3: t2.B1->buf0
//   ph4: t2.A0->buf0 + vmcnt(6)
//   ph5: t2.A1->buf0   ph6: t3.B0->buf1   ph7: t3.B1->buf1
//   ph8: t3.A0->buf1 + vmcnt(6)
// Prologue: t0.{B0,B1,A0,A1}, t1.{B0,B1,A0} + vmcnt(6). Last iter: ph4
// vmcnt(0), stages of t>=NT guarded out.
// ---------------------------------------------------------------------------
__global__ __launch_bounds__(512, 2) void gemm8p(const unsigned short* __restrict__ Ab,
                                                 const unsigned short* __restrict__ Bt,
                                                 float* __restrict__ C) {
    __shared__ __align__(16) char smem[2 * 65536];

    const int tid  = threadIdx.x;
    const int wave = tid >> 6;
    const int lane = tid & 63;

    // XCD-bijective swizzle (nwg = 512, % 8 == 0)
    const int nwg = gridDim.x;
    const int cpx = nwg >> 3;
    const int wg  = (blockIdx.x & 7) * cpx + (blockIdx.x >> 3);
    const int nbn = N_DIM / BN;                 // 16
    const int bm0 = (wg / nbn) * BM;
    const int bn0 = (wg % nbn) * BN;

    const int wr = wave >> 2;                   // 0..1 (M)
    const int wc = wave & 3;                    // 0..3 (N)

    // ---- staging (pre-swizzled global source) ----
    const int srow = tid >> 3;                          // row within 64-row chunk
    const int lsw  = (lane & 7) ^ ((lane >> 3) & 7);    // logical slot fetched
    const unsigned short* gA0 = Ab + (size_t)(bm0 + srow) * K_DIM + lsw * 8;
    const unsigned short* gB0 = Bt + (size_t)(bn0 + srow) * K_DIM + lsw * 8;

    // ---- ds_read addressing (swizzled; conflict-free, proven R3/R5/R6) ----
    const int r16  = lane & 15;
    const int x7   = lane & 7;
    const int ksl0 = (((lane >> 4)    ) ^ x7) * 16;     // kk=0 slot
    const int ksl1 = (((lane >> 4) | 4) ^ x7) * 16;     // kk=1 slot
    const int aRow = (wr * 128 + r16) * 128;            // byte offset, A region
    const int bRow = (wc * 64  + r16) * 128 + 32768;    // byte offset, B region

    f32x4  acc[8][4] = {};
    bf16x8 b[4][2];

#define STAGE_HALF(gbase, opoff, h, t, p) do {                                              \
    char* lds_ = smem + (p) * 65536 + (opoff) + (h) * 16384 + wave * 1024;                  \
    const unsigned short* g_ = (gbase) + (size_t)((h) * 128) * K_DIM + (t) * BK;            \
    __builtin_amdgcn_global_load_lds(                                                        \
        (const __attribute__((address_space(1))) unsigned int*)g_,                           \
        (__attribute__((address_space(3))) unsigned int*)lds_, 16, 0, 0);                    \
    __builtin_amdgcn_global_load_lds(                                                        \
        (const __attribute__((address_space(1))) unsigned int*)(g_ + (size_t)64 * K_DIM),    \
        (__attribute__((address_space(3))) unsigned int*)(lds_ + 8192), 16, 0, 0);           \
} while (0)

#define PHASE(P, Q, LOADB, STAGE_STMT, VM_STMT) do {                                        \
    const char* base_ = smem + (P) * 65536;                                                 \
    bf16x8 a_[2][2];                                                                        \
    if (LOADB) {                                                                            \
        _Pragma("unroll")                                                                   \
        for (int fn = 0; fn < 4; ++fn) {                                                    \
            b[fn][0] = *(const bf16x8*)(base_ + bRow + fn * 2048 + ksl0);                   \
            b[fn][1] = *(const bf16x8*)(base_ + bRow + fn * 2048 + ksl1);                   \
        }                                                                                   \
    }                                                                                       \
    a_[0][0] = *(const bf16x8*)(base_ + aRow + (Q) * 4096 + ksl0);                          \
    a_[0][1] = *(const bf16x8*)(base_ + aRow + (Q) * 4096 + ksl1);                          \
    a_[1][0] = *(const bf16x8*)(base_ + aRow + (Q) * 4096 + 2048 + ksl0);                   \
    a_[1][1] = *(const bf16x8*)(base_ + aRow + (Q) * 4096 + 2048 + ksl1);                   \
    STAGE_STMT;                                                                             \
    __builtin_amdgcn_s_barrier();                                                           \
    asm volatile("s_waitcnt lgkmcnt(0)" ::: "memory");                                      \
    __builtin_amdgcn_sched_barrier(0);                                                      \
    __builtin_amdgcn_s_setprio(1);                                                          \
    _Pragma("unroll")                                                                       \
    for (int fm = 0; fm < 2; ++fm)                                                          \
        _Pragma("unroll")                                                                   \
        for (int fn = 0; fn < 4; ++fn) {                                                    \
            acc[(Q)*2 + fm][fn] = __builtin_amdgcn_mfma_f32_16x16x32_bf16(                  \
                a_[fm][0], b[fn][0], acc[(Q)*2 + fm][fn], 0, 0, 0);                         \
            acc[(Q)*2 + fm][fn] = __builtin_amdgcn_mfma_f32_16x16x32_bf16(                  \
                a_[fm][1], b[fn][1], acc[(Q)*2 + fm][fn], 0, 0, 0);                         \
        }                                                                                   \
    __builtin_amdgcn_s_setprio(0);                                                          \
    VM_STMT;                                                                                \
    __builtin_amdgcn_s_barrier();                                                           \
} while (0)

    // ---- prologue: t0 complete + t1.{B0,B1,A0}; newest 3 halves may fly ----
    STAGE_HALF(gB0, 32768, 0, 0, 0);
    STAGE_HALF(gB0, 32768, 1, 0, 0);
    STAGE_HALF(gA0, 0,     0, 0, 0);
    STAGE_HALF(gA0, 0,     1, 0, 0);
    STAGE_HALF(gB0, 32768, 0, 1, 1);
    STAGE_HALF(gB0, 32768, 1, 1, 1);
    STAGE_HALF(gA0, 0,     0, 1, 1);
    asm volatile("s_waitcnt vmcnt(6)" ::: "memory");
    __builtin_amdgcn_s_barrier();

    for (int u = 0; u < NITER; ++u) {
        const bool last = (u == NITER - 1);
        const int  t1 = 2 * u + 1, t2 = 2 * u + 2, t3 = 2 * u + 3;

        PHASE(0, 0, 1, { STAGE_HALF(gA0, 0, 1, t1, 1); }, {});                 // t1.A1
        PHASE(0, 1, 0, { if (!last) STAGE_HALF(gB0, 32768, 0, t2, 0); }, {});  // t2.B0
        PHASE(0, 2, 0, { if (!last) STAGE_HALF(gB0, 32768, 1, t2, 0); }, {});  // t2.B1
        PHASE(0, 3, 0, { if (!last) STAGE_HALF(gA0, 0, 0, t2, 0); },           // t2.A0
              { if (last) asm volatile("s_waitcnt vmcnt(0)" ::: "memory");
                else      asm volatile("s_waitcnt vmcnt(6)" ::: "memory"); });
        PHASE(1, 0, 1, { if (!last) STAGE_HALF(gA0, 0, 1, t2, 0); }, {});      // t2.A1
        PHASE(1, 1, 0, { if (!last) STAGE_HALF(gB0, 32768, 0, t3, 1); }, {});  // t3.B0
        PHASE(1, 2, 0, { if (!last) STAGE_HALF(gB0, 32768, 1, t3, 1); }, {});  // t3.B1
        PHASE(1, 3, 0, { if (!last) STAGE_HALF(gA0, 0, 0, t3, 1); },           // t3.A0
              { if (!last) asm volatile("s_waitcnt vmcnt(6)" ::: "memory"); });
    }
#undef PHASE
#undef STAGE_HALF

    // ---- R8 epilogue: per-wave LDS transpose -> coalesced dwordx4 stores ----
    // Wave-private scratch (4608 B each, 36.9 KB total); no barriers needed:
    // final K-loop barrier guarantees all waves' ds_reads of smem returned.
    // Stride 68 floats/row: write conflicts 2-way (free, m136); reads 16B-aligned.
    {
        float* scratch = (float*)smem + wave * 1152;    // 1152 floats = 4608 B
        const int crow = (lane >> 4) * 4;
        const int lrow = lane >> 4;
        const int lcol = (lane & 15) * 4;
        float* Crow0 = C + (size_t)(bm0 + wr * 128) * N_DIM + (bn0 + wc * 64);
#pragma unroll
        for (int fm = 0; fm < 8; ++fm) {
            // scatter D-frag into scratch: [16 rows][64 cols], stride 68
#pragma unroll
            for (int fn = 0; fn < 4; ++fn)
#pragma unroll
                for (int r = 0; r < 4; ++r)
                    scratch[(crow + r) * 68 + fn * 16 + r16] = acc[fm][fn][r];
            asm volatile("s_waitcnt lgkmcnt(0)" ::: "memory");
            // read back coalesced, store 16B per lane (256B contiguous / 16 lanes)
#pragma unroll
            for (int j = 0; j < 4; ++j) {
                const int rr = j * 4 + lrow;
                f32x4 v = *(const f32x4*)&scratch[rr * 68 + lcol];
                *(f32x4*)&Crow0[(size_t)(fm * 16 + rr) * N_DIM + lcol] = v;
            }
        }
    }
}

// ---------------------------------------------------------------------------
extern "C" void kernel_launch(void* const* d_in, const int* in_sizes, int n_in,
                              void* d_out, int out_size, void* d_ws, size_t ws_size,
                              hipStream_t stream) {
    const float* x = (const float*)d_in[0];   // (4,2048,2048) fp32
    const float* W = (const float*)d_in[1];   // (4096,2048) fp32
    float* out = (float*)d_out;               // (4,2048,4096) fp32

    unsigned short* xb = (unsigned short*)d_ws;                                      // 32 MB bf16 x
    unsigned short* wt = (unsigned short*)((char*)d_ws + (size_t)M_DIM * K_DIM * 2); // 16 MB WeffT

    const int cvt_blocks = (M_DIM * K_DIM) / 4 / 256;   // 16384
    prep_fused<<<N_DIM / 2 + cvt_blocks, 256, 0, stream>>>(x, W, xb, wt);

    dim3 grid((M_DIM / BM) * (N_DIM / BN));   // 512 blocks
    gemm8p<<<grid, 512, 0, stream>>>(xb, wt, out);
}